// Round 1
// baseline (70.797 us; speedup 1.0000x reference)
//
#include <hip/hip_runtime.h>
#include <stdint.h>

#define NA   3
#define KCH  8      // 5 + NUM_CLASSES
#define BLK  512
#define MAXN 19200  // 3 * 80 * 80

struct ScaleParams {
  const float*   pred;    // (B, 24, H, W)
  const float*   boxes;   // (B, N, 4)
  const int*     labels;  // (B, N)
  const uint8_t* pos;     // (B, N) bool
  const uint8_t* neg;     // (B, N) bool
  int HW;
};

__global__ void zero_out_kernel(float* out) {
  if (threadIdx.x < 4) out[threadIdx.x] = 0.f;
}

__global__ void finalize_kernel(float* out, float invB) {
  if (threadIdx.x == 0) {
    float o = out[1] * invB;
    float c = out[2] * invB;
    float l = out[3] * invB;
    out[0] = o + c + l;
    out[1] = o;
    out[2] = c;
    out[3] = l;
  }
}

__device__ __forceinline__ float softplusf(float x) {
  // logaddexp(0, x) = max(x,0) + log1p(exp(-|x|))
  return fmaxf(x, 0.f) + log1pf(expf(-fabsf(x)));
}

__device__ __forceinline__ float sl1(float d) {
  float ad = fabsf(d);
  return (ad < 1.f) ? 0.5f * d * d : ad - 0.5f;
}

// block-wide sum; result broadcast to all threads. Must be called uniformly.
__device__ __forceinline__ float blockSumF(float v, float* scr) {
  #pragma unroll
  for (int off = 32; off > 0; off >>= 1) v += __shfl_down(v, off);
  int lane = threadIdx.x & 63, w = threadIdx.x >> 6;
  __syncthreads();
  if (lane == 0) scr[w] = v;
  __syncthreads();
  if (threadIdx.x == 0) {
    float r = 0.f;
    #pragma unroll
    for (int i = 0; i < BLK / 64; ++i) r += scr[i];
    scr[0] = r;
  }
  __syncthreads();
  return scr[0];
}

__device__ __forceinline__ int blockSumI(int v, int* scr) {
  #pragma unroll
  for (int off = 32; off > 0; off >>= 1) v += __shfl_down(v, off);
  int lane = threadIdx.x & 63, w = threadIdx.x >> 6;
  __syncthreads();
  if (lane == 0) scr[w] = v;
  __syncthreads();
  if (threadIdx.x == 0) {
    int r = 0;
    #pragma unroll
    for (int i = 0; i < BLK / 64; ++i) r += scr[i];
    scr[0] = r;
  }
  __syncthreads();
  return scr[0];
}

__global__ __launch_bounds__(BLK, 1) void row_loss_kernel(
    ScaleParams p0, ScaleParams p1, ScaleParams p2, int B, float* out) {
  __shared__ float    vals[MAXN];   // neg obj-loss values (0 where not neg)
  __shared__ int      hist[256];
  __shared__ int      wavesum[4];
  __shared__ float    fscr[BLK / 64];
  __shared__ int      iscr[BLK / 64];
  __shared__ unsigned sh_digit;
  __shared__ int      sh_krem;

  const int bid = blockIdx.x;
  const int s = bid % 3;
  const int b = bid / 3;
  const ScaleParams P = (s == 0) ? p0 : (s == 1) ? p1 : p2;
  const int HW = P.HW;
  const int N = NA * HW;
  const int t = threadIdx.x;

  // ---- pass 1: stream obj channel + masks; sparse pos work ----
  int   npos = 0, nneg = 0;
  float pos_obj = 0.f, ce = 0.f, loc = 0.f;

  const float* predb = P.pred + (size_t)b * (NA * KCH) * HW;
  const size_t row = (size_t)b * N;

  for (int a = 0; a < NA; ++a) {
    const float* pa = predb + (size_t)a * KCH * HW;
    const int jb = a * HW;
    for (int cell = t; cell < HW; cell += BLK) {
      const int j = jb + cell;
      const float obj = pa[4 * HW + cell];
      const bool ispos = P.pos[row + j] != 0;
      const bool isneg = P.neg[row + j] != 0;
      const float sp = softplusf(obj);
      vals[j] = isneg ? sp : 0.f;
      nneg += (int)isneg;
      if (ispos) {
        npos += 1;
        pos_obj += sp - obj;  // softplus(obj) - obj
        // class CE (log-softmax over 3 classes)
        const float c0 = pa[5 * HW + cell];
        const float c1 = pa[6 * HW + cell];
        const float c2 = pa[7 * HW + cell];
        const float m = fmaxf(fmaxf(c0, c1), c2);
        const float lse = m + logf(expf(c0 - m) + expf(c1 - m) + expf(c2 - m));
        const int lab = P.labels[row + j];
        const float cl = (lab == 0) ? c0 : (lab == 1) ? c1 : c2;
        ce += lse - cl;
        // smooth-L1 loc loss
        const float* bx = P.boxes + (row + j) * 4;
        const float d0 = pa[0 * HW + cell] - bx[0];
        const float d1 = pa[1 * HW + cell] - bx[1];
        const float d2 = pa[2 * HW + cell] - bx[2];
        const float d3 = pa[3 * HW + cell] - bx[3];
        loc += sl1(d0) + sl1(d1) + sl1(d2) + sl1(d3);
      }
    }
  }
  __syncthreads();  // vals[] complete

  const int   t_npos   = blockSumI(npos, iscr);
  const int   t_nneg   = blockSumI(nneg, iscr);
  const float t_posobj = blockSumF(pos_obj, fscr);
  const float t_ce     = blockSumF(ce, fscr);
  const float t_loc    = blockSumF(loc, fscr);

  const int k = min(3 * t_npos, t_nneg);  // num_neg to mine
  float sel_sum = 0.f;

  if (k > 0) {  // k uniform across block -> barriers safe
    unsigned prefix = 0;
    int krem = k;
    for (int pass = 0; pass < 4; ++pass) {
      const int shift = 24 - 8 * pass;
      for (int i = t; i < 256; i += BLK) hist[i] = 0;
      __syncthreads();
      for (int j = t; j < N; j += BLK) {
        const unsigned bits = __float_as_uint(vals[j]);
        if (pass == 0 || (bits >> (shift + 8)) == prefix)
          atomicAdd(&hist[(bits >> shift) & 0xFFu], 1);
      }
      __syncthreads();
      // parallel suffix scan over 256 bins (first 256 threads meaningful)
      const int h = (t < 256) ? hist[t] : 0;
      int ssum = h;
      #pragma unroll
      for (int off = 1; off < 64; off <<= 1) {
        const int o = __shfl_down(ssum, off);
        if (((t & 63) + off) < 64) ssum += o;
      }
      if (t < 256 && (t & 63) == 0) wavesum[t >> 6] = ssum;
      __syncthreads();
      if (t < 256) {
        int above = 0;
        for (int w2 = (t >> 6) + 1; w2 < 4; ++w2) above += wavesum[w2];
        const int S_incl = ssum + above;    // count with digit >= t (matching prefix)
        const int S_excl = S_incl - h;      // count with digit >  t
        if (S_excl < krem && krem <= S_incl) {
          sh_digit = (unsigned)t;
          sh_krem  = krem - S_excl;
        }
      }
      __syncthreads();
      prefix = (prefix << 8) | sh_digit;
      krem = sh_krem;
    }
    // prefix == bits of the k-th largest value T
    const unsigned Tbits = prefix;
    const float T = __uint_as_float(Tbits);
    float sgt = 0.f;
    for (int j = t; j < N; j += BLK) {
      const float v = vals[j];
      if (__float_as_uint(v) > Tbits) sgt += v;
    }
    const float t_sgt = blockSumF(sgt, fscr);
    sel_sum = t_sgt + (float)krem * T;  // ties at T contribute krem * T
  }

  if (t == 0) {
    const float denom = (float)max(t_npos, 1);
    const float obj_per = (t_posobj + sel_sum) / denom;
    const float cls_per = (t_npos > 0) ? (t_ce / denom) : 0.f;
    const float loc_per = (t_npos > 0) ? (t_loc / (denom * 4.f)) : 0.f;
    atomicAdd(&out[1], obj_per);
    atomicAdd(&out[2], cls_per);
    atomicAdd(&out[3], loc_per);
  }
}

extern "C" void kernel_launch(void* const* d_in, const int* in_sizes, int n_in,
                              void* d_out, int out_size, void* d_ws, size_t ws_size,
                              hipStream_t stream) {
  (void)n_in; (void)d_ws; (void)ws_size; (void)out_size;

  const int HW0 = 80 * 80, HW1 = 40 * 40, HW2 = 20 * 20;
  const int B = in_sizes[0] / (NA * KCH * HW0);

  ScaleParams p0{(const float*)d_in[0],  (const float*)d_in[1],
                 (const int*)d_in[2],    (const uint8_t*)d_in[3],
                 (const uint8_t*)d_in[4], HW0};
  ScaleParams p1{(const float*)d_in[5],  (const float*)d_in[6],
                 (const int*)d_in[7],    (const uint8_t*)d_in[8],
                 (const uint8_t*)d_in[9], HW1};
  ScaleParams p2{(const float*)d_in[10], (const float*)d_in[11],
                 (const int*)d_in[12],   (const uint8_t*)d_in[13],
                 (const uint8_t*)d_in[14], HW2};

  float* out = (float*)d_out;
  zero_out_kernel<<<1, 64, 0, stream>>>(out);
  row_loss_kernel<<<3 * B, BLK, 0, stream>>>(p0, p1, p2, B, out);
  finalize_kernel<<<1, 64, 0, stream>>>(out, 1.f / (float)B);
}

// Round 2
// 65.243 us; speedup vs baseline: 1.0851x; 1.0851x over previous
//
#include <hip/hip_runtime.h>
#include <stdint.h>

#define NA   3
#define KCH  8      // 5 + NUM_CLASSES
#define BLKA 256
#define BLKB 512
#define BLK  512
#define MAXN 19200  // 3 * 80 * 80

struct ScaleParams {
  const float*   pred;    // (B, 24, H, W)
  const float*   boxes;   // (B, N, 4)
  const int*     labels;  // (B, N)
  const uint8_t* pos;     // (B, N) bool
  const uint8_t* neg;     // (B, N) bool
  int HW;
};

__device__ __forceinline__ float softplusf(float x) {
  // logaddexp(0, x) = max(x,0) + log1p(exp(-|x|))
  return fmaxf(x, 0.f) + log1pf(expf(-fabsf(x)));
}

__device__ __forceinline__ float sl1f(float d) {
  float ad = fabsf(d);
  return (ad < 1.f) ? 0.5f * d * d : ad - 0.5f;
}

__device__ __forceinline__ float waveSumF(float v) {
  #pragma unroll
  for (int off = 32; off > 0; off >>= 1) v += __shfl_down(v, off);
  return v;
}

__global__ void zero_out_kernel(float* out) {
  if (threadIdx.x < 4) out[threadIdx.x] = 0.f;
}

__global__ void finalize_kernel(float* out, float invB) {
  if (threadIdx.x == 0) {
    float o = out[1] * invB;
    float c = out[2] * invB;
    float l = out[3] * invB;
    out[0] = o + c + l;
    out[1] = o;
    out[2] = c;
    out[3] = l;
  }
}

// ---------------------------------------------------------------------------
// Kernel A: per-(row, anchor) block. Streams the obj plane + masks once,
// builds an 11-bit (bits[30:20]) count+sum histogram in LDS, flushes nonzero
// bins to the per-row global histogram. Pos-side CE/loc fused here.
// ---------------------------------------------------------------------------
__global__ __launch_bounds__(BLKA) void hist_kernel(
    ScaleParams p0, ScaleParams p1, ScaleParams p2, int B,
    unsigned* g_cnt, float* g_sum, float* g_scal) {
  __shared__ unsigned hc[2048];
  __shared__ float    hs[2048];

  const int x = blockIdx.x;
  const int s = x / (3 * B);         // scale (heavy scale 0 first)
  const int rem = x % (3 * B);
  const int b = rem / 3, a = rem % 3;
  const int r = s * B + b;           // global row id
  const ScaleParams P = (s == 0) ? p0 : (s == 1) ? p1 : p2;
  const int HW = P.HW;
  const int N = NA * HW;
  const int t = threadIdx.x;

  for (int i = t; i < 2048; i += BLKA) { hc[i] = 0u; hs[i] = 0.f; }
  __syncthreads();

  const float* pa = P.pred + ((size_t)b * NA + a) * KCH * HW;
  const size_t row = (size_t)b * N;
  const int jb = a * HW;

  float npos = 0.f, nneg = 0.f, posobj = 0.f, ce = 0.f, loc = 0.f;

  for (int c = t * 4; c < HW; c += BLKA * 4) {
    const float4 o4 = *(const float4*)(pa + 4 * HW + c);
    const uchar4 pm = *(const uchar4*)(P.pos + row + jb + c);
    const uchar4 nm = *(const uchar4*)(P.neg + row + jb + c);
    #pragma unroll
    for (int q = 0; q < 4; ++q) {
      const float obj = (&o4.x)[q];
      const float sp = softplusf(obj);
      if ((&nm.x)[q]) {
        nneg += 1.f;
        const unsigned key = __float_as_uint(sp);
        atomicAdd(&hc[key >> 20], 1u);
        atomicAdd(&hs[key >> 20], sp);
      }
      if ((&pm.x)[q]) {
        npos += 1.f;
        posobj += sp - obj;
        const int cell = c + q;
        const float c0 = pa[5 * HW + cell];
        const float c1 = pa[6 * HW + cell];
        const float c2 = pa[7 * HW + cell];
        const float m = fmaxf(fmaxf(c0, c1), c2);
        const float lse = m + logf(expf(c0 - m) + expf(c1 - m) + expf(c2 - m));
        const int lab = P.labels[row + jb + cell];
        ce += lse - ((lab == 0) ? c0 : (lab == 1) ? c1 : c2);
        const float4 bx = *(const float4*)(P.boxes + ((size_t)(row + jb + cell)) * 4);
        loc += sl1f(pa[0 * HW + cell] - bx.x) + sl1f(pa[1 * HW + cell] - bx.y)
             + sl1f(pa[2 * HW + cell] - bx.z) + sl1f(pa[3 * HW + cell] - bx.w);
      }
    }
  }

  // per-wave reduce, lane-0 atomics (counts as floats: exact below 2^24)
  npos = waveSumF(npos); nneg = waveSumF(nneg); posobj = waveSumF(posobj);
  ce = waveSumF(ce); loc = waveSumF(loc);
  if ((t & 63) == 0) {
    atomicAdd(&g_scal[r * 8 + 0], npos);
    atomicAdd(&g_scal[r * 8 + 1], nneg);
    atomicAdd(&g_scal[r * 8 + 2], posobj);
    atomicAdd(&g_scal[r * 8 + 3], ce);
    atomicAdd(&g_scal[r * 8 + 4], loc);
  }

  __syncthreads();
  for (int i = t; i < 2048; i += BLKA) {
    const unsigned cc = hc[i];
    if (cc) {
      atomicAdd(&g_cnt[(size_t)r * 2048 + i], cc);
      atomicAdd(&g_sum[(size_t)r * 2048 + i], hs[i]);
    }
  }
}

// ---------------------------------------------------------------------------
// Kernel B helper: given per-thread Q bins (count, value-sum) of an ordered
// histogram, find bin holding the krem-th largest, remaining krem, and the
// accumulated sum of all values in strictly-higher bins. Uniform call.
// ---------------------------------------------------------------------------
template<int Q>
__device__ __forceinline__ void selectDigit(const unsigned* cb, const float* sb,
    int krem_in, float sa_in, int* iwav, float* fwav,
    int* sh_dig, int* sh_krem, float* sh_sa) {
  const int t = threadIdx.x, lane = t & 63, w = t >> 6;
  int c_t = 0; float s_t = 0.f;
  #pragma unroll
  for (int q = 0; q < Q; ++q) { c_t += (int)cb[q]; s_t += sb[q]; }
  // wave-level inclusive suffix scan
  int ci = c_t; float si = s_t;
  #pragma unroll
  for (int off = 1; off < 64; off <<= 1) {
    const int co = __shfl_down(ci, off);
    const float so = __shfl_down(si, off);
    if (lane + off < 64) { ci += co; si += so; }
  }
  __syncthreads();                  // protect iwav/fwav reuse across calls
  if (lane == 0) { iwav[w] = ci; fwav[w] = si; }
  __syncthreads();
  int ac = 0; float as = 0.f;
  for (int w2 = w + 1; w2 < BLKB / 64; ++w2) { ac += iwav[w2]; as += fwav[w2]; }
  int   cum_c = (ci - c_t) + ac;    // count in bins strictly above this thread's top bin
  float cum_s = (si - s_t) + as;
  #pragma unroll
  for (int q = Q - 1; q >= 0; --q) {
    const int cq = (int)cb[q];
    if (cum_c < krem_in && krem_in <= cum_c + cq) {   // unique bracket
      *sh_dig = t * Q + q;
      *sh_krem = krem_in - cum_c;
      *sh_sa = sa_in + cum_s;
    }
    cum_c += cq; cum_s += sb[q];
  }
  __syncthreads();
}

// ---------------------------------------------------------------------------
// Kernel B: one block per row. Stage 1 from global hist; 2 filtered re-sweeps
// (bits[19:9] then bits[8:0]) recomputing softplus from pred (L2-resident).
// ---------------------------------------------------------------------------
__global__ __launch_bounds__(BLKB, 1) void select_kernel(
    ScaleParams p0, ScaleParams p1, ScaleParams p2, int B,
    const unsigned* g_cnt, const float* g_sum, const float* g_scal, float* out) {
  __shared__ int   h2c[2048];
  __shared__ float h2s[2048];
  __shared__ int   iwav[BLKB / 64];
  __shared__ float fwav[BLKB / 64];
  __shared__ int   sh_dig, sh_krem;
  __shared__ float sh_sa;

  const int r = blockIdx.x;
  const int s = r / B, b = r % B;
  const ScaleParams P = (s == 0) ? p0 : (s == 1) ? p1 : p2;
  const int HW = P.HW, N = NA * HW;
  const int t = threadIdx.x;

  const float sc_np = g_scal[r * 8 + 0];
  const float sc_nn = g_scal[r * 8 + 1];
  const float sc_po = g_scal[r * 8 + 2];
  const float sc_ce = g_scal[r * 8 + 3];
  const float sc_lc = g_scal[r * 8 + 4];
  const int npos = (int)sc_np, nneg = (int)sc_nn;
  const int k = min(3 * npos, nneg);

  float sel_sum = 0.f;
  if (k > 0) {  // uniform across block
    // ---- stage 1: bits[30:20] from global per-row histogram ----
    unsigned cb[4]; float sb[4];
    const uint4  cv = *(const uint4*)(g_cnt + (size_t)r * 2048 + t * 4);
    const float4 sv = *(const float4*)(g_sum + (size_t)r * 2048 + t * 4);
    cb[0] = cv.x; cb[1] = cv.y; cb[2] = cv.z; cb[3] = cv.w;
    sb[0] = sv.x; sb[1] = sv.y; sb[2] = sv.z; sb[3] = sv.w;
    selectDigit<4>(cb, sb, k, 0.f, iwav, fwav, &sh_dig, &sh_krem, &sh_sa);
    const int bin1 = sh_dig; const int krem1 = sh_krem; const float sa1 = sh_sa;

    const float* predb = P.pred + (size_t)b * (NA * KCH) * HW;
    const size_t row = (size_t)b * N;

    // ---- stage 2: bits[19:9] among values with top-11 == bin1 ----
    for (int i = t; i < 2048; i += BLKB) { h2c[i] = 0; h2s[i] = 0.f; }
    __syncthreads();
    for (int c4 = t * 4; c4 < N; c4 += BLKB * 4) {
      const int a = c4 / HW, cell = c4 - a * HW;
      const float4 o4 = *(const float4*)(predb + (size_t)a * KCH * HW + 4 * HW + cell);
      const uchar4 nm = *(const uchar4*)(P.neg + row + c4);
      #pragma unroll
      for (int q = 0; q < 4; ++q) {
        if ((&nm.x)[q]) {
          const float sp = softplusf((&o4.x)[q]);
          const unsigned key = __float_as_uint(sp);
          if ((int)(key >> 20) == bin1) {
            atomicAdd(&h2c[(key >> 9) & 2047], 1);
            atomicAdd(&h2s[(key >> 9) & 2047], sp);
          }
        }
      }
    }
    __syncthreads();
    #pragma unroll
    for (int q = 0; q < 4; ++q) { cb[q] = (unsigned)h2c[t * 4 + q]; sb[q] = h2s[t * 4 + q]; }
    selectDigit<4>(cb, sb, krem1, sa1, iwav, fwav, &sh_dig, &sh_krem, &sh_sa);
    const int d2 = sh_dig; const int krem2 = sh_krem; const float sa2 = sh_sa;
    const unsigned pre22 = ((unsigned)bin1 << 11) | (unsigned)d2;

    // ---- stage 3: bits[8:0] among values with top-22 == pre22 ----
    for (int i = t; i < 512; i += BLKB) { h2c[i] = 0; h2s[i] = 0.f; }
    __syncthreads();
    for (int c4 = t * 4; c4 < N; c4 += BLKB * 4) {
      const int a = c4 / HW, cell = c4 - a * HW;
      const float4 o4 = *(const float4*)(predb + (size_t)a * KCH * HW + 4 * HW + cell);
      const uchar4 nm = *(const uchar4*)(P.neg + row + c4);
      #pragma unroll
      for (int q = 0; q < 4; ++q) {
        if ((&nm.x)[q]) {
          const float sp = softplusf((&o4.x)[q]);
          const unsigned key = __float_as_uint(sp);
          if ((key >> 9) == pre22) {
            atomicAdd(&h2c[key & 511], 1);
            atomicAdd(&h2s[key & 511], sp);
          }
        }
      }
    }
    __syncthreads();
    unsigned cb1[1]; float sb1[1];
    cb1[0] = (unsigned)h2c[t]; sb1[0] = h2s[t];
    selectDigit<1>(cb1, sb1, krem2, sa2, iwav, fwav, &sh_dig, &sh_krem, &sh_sa);
    const int d3 = sh_dig; const int krem3 = sh_krem; const float sa3 = sh_sa;
    const unsigned Tbits = (pre22 << 9) | (unsigned)d3;
    sel_sum = sa3 + (float)krem3 * __uint_as_float(Tbits);
  }

  if (t == 0) {
    const float denom = (float)max(npos, 1);
    const float obj_per = (sc_po + sel_sum) / denom;
    const float cls_per = (npos > 0) ? sc_ce / denom : 0.f;
    const float loc_per = (npos > 0) ? sc_lc / (denom * 4.f) : 0.f;
    atomicAdd(&out[1], obj_per);
    atomicAdd(&out[2], cls_per);
    atomicAdd(&out[3], loc_per);
  }
}

// ---------------------------------------------------------------------------
// Fallback (round-1 kernel) — used only if d_ws is too small.
// ---------------------------------------------------------------------------
__device__ __forceinline__ float blockSumF(float v, float* scr) {
  #pragma unroll
  for (int off = 32; off > 0; off >>= 1) v += __shfl_down(v, off);
  int lane = threadIdx.x & 63, w = threadIdx.x >> 6;
  __syncthreads();
  if (lane == 0) scr[w] = v;
  __syncthreads();
  if (threadIdx.x == 0) {
    float r = 0.f;
    #pragma unroll
    for (int i = 0; i < BLK / 64; ++i) r += scr[i];
    scr[0] = r;
  }
  __syncthreads();
  return scr[0];
}

__device__ __forceinline__ int blockSumI(int v, int* scr) {
  #pragma unroll
  for (int off = 32; off > 0; off >>= 1) v += __shfl_down(v, off);
  int lane = threadIdx.x & 63, w = threadIdx.x >> 6;
  __syncthreads();
  if (lane == 0) scr[w] = v;
  __syncthreads();
  if (threadIdx.x == 0) {
    int r = 0;
    #pragma unroll
    for (int i = 0; i < BLK / 64; ++i) r += scr[i];
    scr[0] = r;
  }
  __syncthreads();
  return scr[0];
}

__global__ __launch_bounds__(BLK, 1) void row_loss_kernel(
    ScaleParams p0, ScaleParams p1, ScaleParams p2, int B, float* out) {
  __shared__ float    vals[MAXN];
  __shared__ int      hist[256];
  __shared__ int      wavesum[4];
  __shared__ float    fscr[BLK / 64];
  __shared__ int      iscr[BLK / 64];
  __shared__ unsigned sh_digit;
  __shared__ int      sh_kremf;

  const int bid = blockIdx.x;
  const int s = bid % 3;
  const int b = bid / 3;
  const ScaleParams P = (s == 0) ? p0 : (s == 1) ? p1 : p2;
  const int HW = P.HW;
  const int N = NA * HW;
  const int t = threadIdx.x;

  int   npos = 0, nneg = 0;
  float pos_obj = 0.f, ce = 0.f, loc = 0.f;

  const float* predb = P.pred + (size_t)b * (NA * KCH) * HW;
  const size_t row = (size_t)b * N;

  for (int a = 0; a < NA; ++a) {
    const float* pa = predb + (size_t)a * KCH * HW;
    const int jb = a * HW;
    for (int cell = t; cell < HW; cell += BLK) {
      const int j = jb + cell;
      const float obj = pa[4 * HW + cell];
      const bool ispos = P.pos[row + j] != 0;
      const bool isneg = P.neg[row + j] != 0;
      const float sp = softplusf(obj);
      vals[j] = isneg ? sp : 0.f;
      nneg += (int)isneg;
      if (ispos) {
        npos += 1;
        pos_obj += sp - obj;
        const float c0 = pa[5 * HW + cell];
        const float c1 = pa[6 * HW + cell];
        const float c2 = pa[7 * HW + cell];
        const float m = fmaxf(fmaxf(c0, c1), c2);
        const float lse = m + logf(expf(c0 - m) + expf(c1 - m) + expf(c2 - m));
        const int lab = P.labels[row + j];
        const float cl = (lab == 0) ? c0 : (lab == 1) ? c1 : c2;
        ce += lse - cl;
        const float* bx = P.boxes + (row + j) * 4;
        loc += sl1f(pa[0 * HW + cell] - bx[0]) + sl1f(pa[1 * HW + cell] - bx[1])
             + sl1f(pa[2 * HW + cell] - bx[2]) + sl1f(pa[3 * HW + cell] - bx[3]);
      }
    }
  }
  __syncthreads();

  const int   t_npos   = blockSumI(npos, iscr);
  const int   t_nneg   = blockSumI(nneg, iscr);
  const float t_posobj = blockSumF(pos_obj, fscr);
  const float t_ce     = blockSumF(ce, fscr);
  const float t_loc    = blockSumF(loc, fscr);

  const int k = min(3 * t_npos, t_nneg);
  float sel_sum = 0.f;

  if (k > 0) {
    unsigned prefix = 0;
    int krem = k;
    for (int pass = 0; pass < 4; ++pass) {
      const int shift = 24 - 8 * pass;
      for (int i = t; i < 256; i += BLK) hist[i] = 0;
      __syncthreads();
      for (int j = t; j < N; j += BLK) {
        const unsigned bits = __float_as_uint(vals[j]);
        if (pass == 0 || (bits >> (shift + 8)) == prefix)
          atomicAdd(&hist[(bits >> shift) & 0xFFu], 1);
      }
      __syncthreads();
      const int h = (t < 256) ? hist[t] : 0;
      int ssum = h;
      #pragma unroll
      for (int off = 1; off < 64; off <<= 1) {
        const int o = __shfl_down(ssum, off);
        if (((t & 63) + off) < 64) ssum += o;
      }
      if (t < 256 && (t & 63) == 0) wavesum[t >> 6] = ssum;
      __syncthreads();
      if (t < 256) {
        int above = 0;
        for (int w2 = (t >> 6) + 1; w2 < 4; ++w2) above += wavesum[w2];
        const int S_incl = ssum + above;
        const int S_excl = S_incl - h;
        if (S_excl < krem && krem <= S_incl) {
          sh_digit = (unsigned)t;
          sh_kremf = krem - S_excl;
        }
      }
      __syncthreads();
      prefix = (prefix << 8) | sh_digit;
      krem = sh_kremf;
    }
    const unsigned Tbits = prefix;
    const float T = __uint_as_float(Tbits);
    float sgt = 0.f;
    for (int j = t; j < N; j += BLK) {
      const float v = vals[j];
      if (__float_as_uint(v) > Tbits) sgt += v;
    }
    const float t_sgt = blockSumF(sgt, fscr);
    sel_sum = t_sgt + (float)krem * T;
  }

  if (t == 0) {
    const float denom = (float)max(t_npos, 1);
    const float obj_per = (t_posobj + sel_sum) / denom;
    const float cls_per = (t_npos > 0) ? (t_ce / denom) : 0.f;
    const float loc_per = (t_npos > 0) ? (t_loc / (denom * 4.f)) : 0.f;
    atomicAdd(&out[1], obj_per);
    atomicAdd(&out[2], cls_per);
    atomicAdd(&out[3], loc_per);
  }
}

extern "C" void kernel_launch(void* const* d_in, const int* in_sizes, int n_in,
                              void* d_out, int out_size, void* d_ws, size_t ws_size,
                              hipStream_t stream) {
  (void)n_in; (void)out_size;

  const int HW0 = 80 * 80, HW1 = 40 * 40, HW2 = 20 * 20;
  const int B = in_sizes[0] / (NA * KCH * HW0);
  const int R = 3 * B;

  ScaleParams p0{(const float*)d_in[0],  (const float*)d_in[1],
                 (const int*)d_in[2],    (const uint8_t*)d_in[3],
                 (const uint8_t*)d_in[4], HW0};
  ScaleParams p1{(const float*)d_in[5],  (const float*)d_in[6],
                 (const int*)d_in[7],    (const uint8_t*)d_in[8],
                 (const uint8_t*)d_in[9], HW1};
  ScaleParams p2{(const float*)d_in[10], (const float*)d_in[11],
                 (const int*)d_in[12],   (const uint8_t*)d_in[13],
                 (const uint8_t*)d_in[14], HW2};

  float* out = (float*)d_out;
  zero_out_kernel<<<1, 64, 0, stream>>>(out);

  const size_t histBytes = (size_t)R * 2048 * 4;
  const size_t need = histBytes * 2 + (size_t)R * 32;

  if (ws_size >= need) {
    unsigned* g_cnt = (unsigned*)d_ws;
    float*    g_sum = (float*)((char*)d_ws + histBytes);
    float*    g_scal = (float*)((char*)d_ws + 2 * histBytes);
    hipMemsetAsync(d_ws, 0, need, stream);
    hist_kernel<<<3 * R, BLKA, 0, stream>>>(p0, p1, p2, B, g_cnt, g_sum, g_scal);
    select_kernel<<<R, BLKB, 0, stream>>>(p0, p1, p2, B, g_cnt, g_sum, g_scal, out);
  } else {
    row_loss_kernel<<<R, BLK, 0, stream>>>(p0, p1, p2, B, out);
  }

  finalize_kernel<<<1, 64, 0, stream>>>(out, 1.f / (float)B);
}

// Round 3
// 41.451 us; speedup vs baseline: 1.7079x; 1.5740x over previous
//
#include <hip/hip_runtime.h>
#include <stdint.h>

#define NA   3
#define KCH  8       // 5 + NUM_CLASSES
#define BLKM 1024
#define NW   (BLKM / 64)
#define MAXN 19200   // 3 * 80 * 80

struct ScaleParams {
  const float*   pred;    // (B, 24, H, W)
  const float*   boxes;   // (B, N, 4)
  const int*     labels;  // (B, N)
  const uint8_t* pos;     // (B, N) bool
  const uint8_t* neg;     // (B, N) bool
  int HW;
};

__device__ __forceinline__ float softplusf(float x) {
  // logaddexp(0, x) = max(x,0) + log1p(exp(-|x|))
  return fmaxf(x, 0.f) + log1pf(expf(-fabsf(x)));
}

__device__ __forceinline__ float sl1f(float d) {
  float ad = fabsf(d);
  return (ad < 1.f) ? 0.5f * d * d : ad - 0.5f;
}

__device__ __forceinline__ float waveSumF(float v) {
  #pragma unroll
  for (int off = 32; off > 0; off >>= 1) v += __shfl_down(v, off);
  return v;
}

__global__ void zero_kernel(float* out, unsigned* done) {
  if (threadIdx.x < 4) out[threadIdx.x] = 0.f;
  if (threadIdx.x == 0) *done = 0u;
}

// Given per-thread Q consecutive bins (count, value-sum) of an ascending-key
// histogram, find the bin containing the krem-th LARGEST element, the
// remaining count inside that bin, and the value-sum of all strictly-higher
// bins (accumulated onto sa_in). Block-uniform call; results in sh_*.
template<int Q>
__device__ __forceinline__ void selectDigit(const unsigned* cb, const float* sb,
    int krem_in, float sa_in, int* iwav, float* fwav,
    int* sh_dig, int* sh_krem, float* sh_sa) {
  const int t = threadIdx.x, lane = t & 63, w = t >> 6;
  int c_t = 0; float s_t = 0.f;
  #pragma unroll
  for (int q = 0; q < Q; ++q) { c_t += (int)cb[q]; s_t += sb[q]; }
  // wave-level inclusive suffix scan (lane L holds sum over lanes L..63)
  int ci = c_t; float si = s_t;
  #pragma unroll
  for (int off = 1; off < 64; off <<= 1) {
    const int   co = __shfl_down(ci, off);
    const float so = __shfl_down(si, off);
    if (lane + off < 64) { ci += co; si += so; }
  }
  __syncthreads();                 // protect iwav/fwav reuse across calls
  if (lane == 0) { iwav[w] = ci; fwav[w] = si; }
  __syncthreads();
  int ac = 0; float as = 0.f;
  for (int w2 = w + 1; w2 < NW; ++w2) { ac += iwav[w2]; as += fwav[w2]; }
  int   cum_c = (ci - c_t) + ac;   // count in bins strictly above this thread's top bin
  float cum_s = (si - s_t) + as;
  #pragma unroll
  for (int q = Q - 1; q >= 0; --q) {
    const int cq = (int)cb[q];
    if (cq > 0 && cum_c < krem_in && krem_in <= cum_c + cq) {  // unique bracket
      *sh_dig  = t * Q + q;
      *sh_krem = krem_in - cum_c;
      *sh_sa   = sa_in + cum_s;
    }
    cum_c += cq; cum_s += sb[q];
  }
  __syncthreads();
}

__global__ __launch_bounds__(BLKM, 1) void fused_kernel(
    ScaleParams p0, ScaleParams p1, ScaleParams p2,
    int B, int R, float invB, float* out, unsigned* done) {
  __shared__ float    vals[MAXN];   // sp where neg, 0 elsewhere
  __shared__ unsigned hc[2048];
  __shared__ float    hs[2048];
  __shared__ int      iwav[NW];
  __shared__ float    fwav[NW];
  __shared__ float    swav[NW][5];
  __shared__ int      sh_dig, sh_krem;
  __shared__ float    sh_sa;
  __shared__ float    bc[5];

  const int r = blockIdx.x;
  const int s = r / B, b = r % B;   // heavy scale-0 rows dispatched first
  const ScaleParams P = (s == 0) ? p0 : (s == 1) ? p1 : p2;
  const int HW = P.HW, N = NA * HW;
  const int t = threadIdx.x, lane = t & 63, w = t >> 6;

  for (int i = t; i < 2048; i += BLKM) { hc[i] = 0u; hs[i] = 0.f; }
  __syncthreads();

  const float* predb = P.pred + (size_t)b * (NA * KCH) * HW;
  const size_t row = (size_t)b * N;
  float npos = 0.f, nneg = 0.f, posobj = 0.f, ce = 0.f, loc = 0.f;

  // ---- sweep 1 (global): obj + masks; fused sparse pos work ----
  for (int c4 = t * 4; c4 < N; c4 += BLKM * 4) {
    const int a = (c4 >= HW) + (c4 >= 2 * HW);
    const int cell = c4 - a * HW;
    const float* pa = predb + (size_t)a * KCH * HW;
    const float4 o4 = *(const float4*)(pa + 4 * HW + cell);
    const uchar4 pm = *(const uchar4*)(P.pos + row + c4);
    const uchar4 nm = *(const uchar4*)(P.neg + row + c4);
    float4 v4;
    #pragma unroll
    for (int q = 0; q < 4; ++q) {
      const float obj = (&o4.x)[q];
      const float sp = softplusf(obj);
      const bool isneg = (&nm.x)[q] != 0;
      (&v4.x)[q] = isneg ? sp : 0.f;
      if (isneg) {
        nneg += 1.f;
        const unsigned key = __float_as_uint(sp);
        atomicAdd(&hc[key >> 20], 1u);
        atomicAdd(&hs[key >> 20], sp);
      }
      if ((&pm.x)[q]) {
        npos += 1.f;
        posobj += sp - obj;
        const int cq = cell + q;
        const float c0 = pa[5 * HW + cq];
        const float c1 = pa[6 * HW + cq];
        const float c2 = pa[7 * HW + cq];
        const float m = fmaxf(fmaxf(c0, c1), c2);
        const float lse = m + logf(expf(c0 - m) + expf(c1 - m) + expf(c2 - m));
        const int lab = P.labels[row + c4 + q];
        ce += lse - ((lab == 0) ? c0 : (lab == 1) ? c1 : c2);
        const float4 bx = *(const float4*)(P.boxes + (size_t)(row + c4 + q) * 4);
        loc += sl1f(pa[0 * HW + cq] - bx.x) + sl1f(pa[1 * HW + cq] - bx.y)
             + sl1f(pa[2 * HW + cq] - bx.z) + sl1f(pa[3 * HW + cq] - bx.w);
      }
    }
    *(float4*)&vals[c4] = v4;
  }

  // ---- block-reduce the 5 scalars ----
  npos = waveSumF(npos); nneg = waveSumF(nneg); posobj = waveSumF(posobj);
  ce = waveSumF(ce); loc = waveSumF(loc);
  if (lane == 0) {
    swav[w][0] = npos; swav[w][1] = nneg; swav[w][2] = posobj;
    swav[w][3] = ce;   swav[w][4] = loc;
  }
  __syncthreads();
  if (t < 5) {
    float acc = 0.f;
    #pragma unroll
    for (int w2 = 0; w2 < NW; ++w2) acc += swav[w2][t];
    bc[t] = acc;
  }
  __syncthreads();
  const int   npos_i = (int)bc[0], nneg_i = (int)bc[1];
  const float t_posobj = bc[2], t_ce = bc[3], t_loc = bc[4];
  const int k = min(3 * npos_i, nneg_i);

  float sel_sum = 0.f;
  if (k > 0) {  // block-uniform
    // ---- stage 1: bits[30:20], histogram already built ----
    unsigned cb[2]; float sb[2];
    cb[0] = hc[2 * t]; cb[1] = hc[2 * t + 1];
    sb[0] = hs[2 * t]; sb[1] = hs[2 * t + 1];
    selectDigit<2>(cb, sb, k, 0.f, iwav, fwav, &sh_dig, &sh_krem, &sh_sa);
    const int bin1 = sh_dig; const int krem1 = sh_krem; const float sa1 = sh_sa;

    // ---- stage 2: bits[19:9] among values in bin1 (LDS sweep) ----
    for (int i = t; i < 2048; i += BLKM) { hc[i] = 0u; hs[i] = 0.f; }
    __syncthreads();
    for (int j4 = t * 4; j4 < N; j4 += BLKM * 4) {
      const float4 v = *(const float4*)&vals[j4];
      #pragma unroll
      for (int q = 0; q < 4; ++q) {
        const float x = (&v.x)[q];
        const unsigned key = __float_as_uint(x);
        if ((int)(key >> 20) == bin1) {
          atomicAdd(&hc[(key >> 9) & 2047], 1u);
          atomicAdd(&hs[(key >> 9) & 2047], x);
        }
      }
    }
    __syncthreads();
    cb[0] = hc[2 * t]; cb[1] = hc[2 * t + 1];
    sb[0] = hs[2 * t]; sb[1] = hs[2 * t + 1];
    selectDigit<2>(cb, sb, krem1, sa1, iwav, fwav, &sh_dig, &sh_krem, &sh_sa);

    // 22-bit prefix (8 exp + 14 mantissa bits): tie-tail approximated by the
    // bin's lower edge; error < krem * T * 2^-14 — far below the threshold.
    const unsigned Tbits = (((unsigned)bin1 << 11) | (unsigned)sh_dig) << 9;
    sel_sum = sh_sa + (float)sh_krem * __uint_as_float(Tbits);
  }

  if (t == 0) {
    const float denom = (float)max(npos_i, 1);
    atomicAdd(&out[1], (t_posobj + sel_sum) / denom);
    if (npos_i > 0) {
      atomicAdd(&out[2], t_ce / denom);
      atomicAdd(&out[3], t_loc / (denom * 4.f));
    }
    __threadfence();
    const unsigned old = atomicAdd(done, 1u);
    if (old == (unsigned)(R - 1)) {   // last block finalizes in place
      const float o = atomicAdd(&out[1], 0.f) * invB;
      const float c = atomicAdd(&out[2], 0.f) * invB;
      const float l = atomicAdd(&out[3], 0.f) * invB;
      out[0] = o + c + l;
      out[1] = o;
      out[2] = c;
      out[3] = l;
    }
  }
}

extern "C" void kernel_launch(void* const* d_in, const int* in_sizes, int n_in,
                              void* d_out, int out_size, void* d_ws, size_t ws_size,
                              hipStream_t stream) {
  (void)n_in; (void)out_size; (void)ws_size;

  const int HW0 = 80 * 80, HW1 = 40 * 40, HW2 = 20 * 20;
  const int B = in_sizes[0] / (NA * KCH * HW0);
  const int R = 3 * B;

  ScaleParams p0{(const float*)d_in[0],  (const float*)d_in[1],
                 (const int*)d_in[2],    (const uint8_t*)d_in[3],
                 (const uint8_t*)d_in[4], HW0};
  ScaleParams p1{(const float*)d_in[5],  (const float*)d_in[6],
                 (const int*)d_in[7],    (const uint8_t*)d_in[8],
                 (const uint8_t*)d_in[9], HW1};
  ScaleParams p2{(const float*)d_in[10], (const float*)d_in[11],
                 (const int*)d_in[12],   (const uint8_t*)d_in[13],
                 (const uint8_t*)d_in[14], HW2};

  float* out = (float*)d_out;
  unsigned* done = (unsigned*)d_ws;

  zero_kernel<<<1, 64, 0, stream>>>(out, done);
  fused_kernel<<<R, BLKM, 0, stream>>>(p0, p1, p2, B, R, 1.f / (float)B, out, done);
}

// Round 4
// 36.653 us; speedup vs baseline: 1.9316x; 1.1309x over previous
//
#include <hip/hip_runtime.h>
#include <stdint.h>

#define NA   3
#define KCH  8       // 5 + NUM_CLASSES
#define BLK  512
#define NW   (BLK / 64)
#define QCAP 1024    // max pos anchors per row (expected ~192, 60 sigma margin)

#define LOG2E 1.4426950408889634f
#define LN2   0.6931471805599453f

struct ScaleParams {
  const float*   pred;    // (B, 24, H, W)
  const float*   boxes;   // (B, N, 4)
  const int*     labels;  // (B, N)
  const uint8_t* pos;     // (B, N) bool
  const uint8_t* neg;     // (B, N) bool
  int HW;
};

__device__ __forceinline__ float fexp2(float x) { return __builtin_amdgcn_exp2f(x); }
__device__ __forceinline__ float flog2(float x) { return __builtin_amdgcn_logf(x); }

// logaddexp(0,x) = max(x,0) + log1p(exp(-|x|)), native exp2/log2 (~1e-6 rel)
__device__ __forceinline__ float softplus_fast(float x) {
  const float t = fexp2(-fabsf(x) * LOG2E);
  return fmaxf(x, 0.f) + flog2(1.f + t) * LN2;
}

__device__ __forceinline__ float sl1f(float d) {
  float ad = fabsf(d);
  return (ad < 1.f) ? 0.5f * d * d : ad - 0.5f;
}

// block-wide sum, broadcast to all threads. Leading sync protects scr reuse.
__device__ __forceinline__ float blockSum(float v, float* scr) {
  #pragma unroll
  for (int off = 32; off > 0; off >>= 1) v += __shfl_down(v, off);
  const int lane = threadIdx.x & 63, w = threadIdx.x >> 6;
  __syncthreads();
  if (lane == 0) scr[w] = v;
  __syncthreads();
  float r = 0.f;
  #pragma unroll
  for (int i = 0; i < NW; ++i) r += scr[i];   // same-address LDS broadcast
  return r;
}

__global__ void zero_kernel(float* out, unsigned* done) {
  if (threadIdx.x < 4) out[threadIdx.x] = 0.f;
  if (threadIdx.x == 0) *done = 0u;
}

// Given per-thread Q consecutive bins (count, value-sum) of an ascending-key
// histogram, find the bin containing the krem-th LARGEST element, remaining
// count inside it, and value-sum of all strictly-higher bins (+ sa_in).
// Block-uniform call; results in sh_*.
template<int Q>
__device__ __forceinline__ void selectDigit(const unsigned* cb, const float* sb,
    int krem_in, float sa_in, int* iwav, float* fwav,
    int* sh_dig, int* sh_krem, float* sh_sa) {
  const int t = threadIdx.x, lane = t & 63, w = t >> 6;
  int c_t = 0; float s_t = 0.f;
  #pragma unroll
  for (int q = 0; q < Q; ++q) { c_t += (int)cb[q]; s_t += sb[q]; }
  // wave-level inclusive suffix scan (lane L holds sum over lanes L..63)
  int ci = c_t; float si = s_t;
  #pragma unroll
  for (int off = 1; off < 64; off <<= 1) {
    const int   co = __shfl_down(ci, off);
    const float so = __shfl_down(si, off);
    if (lane + off < 64) { ci += co; si += so; }
  }
  __syncthreads();                 // protect iwav/fwav reuse across calls
  if (lane == 0) { iwav[w] = ci; fwav[w] = si; }
  __syncthreads();
  int ac = 0; float as = 0.f;
  for (int w2 = w + 1; w2 < NW; ++w2) { ac += iwav[w2]; as += fwav[w2]; }
  int   cum_c = (ci - c_t) + ac;   // strictly above this thread's top bin
  float cum_s = (si - s_t) + as;
  #pragma unroll
  for (int q = Q - 1; q >= 0; --q) {
    const int cq = (int)cb[q];
    if (cq > 0 && cum_c < krem_in && krem_in <= cum_c + cq) {  // unique bracket
      *sh_dig  = t * Q + q;
      *sh_krem = krem_in - cum_c;
      *sh_sa   = sa_in + cum_s;
    }
    cum_c += cq; cum_s += sb[q];
  }
  __syncthreads();
}

__global__ __launch_bounds__(BLK) void fused_kernel(
    ScaleParams p0, ScaleParams p1, ScaleParams p2,
    int B, int R, float invB, float* out, unsigned* done) {
  __shared__ unsigned hc[2048];
  __shared__ float    hs[2048];
  __shared__ int      queue[QCAP];
  __shared__ int      sh_qn;
  __shared__ int      iwav[NW];
  __shared__ float    fwav[NW];
  __shared__ float    fscr[NW];
  __shared__ int      sh_dig, sh_krem;
  __shared__ float    sh_sa;

  const int r = blockIdx.x;
  const int s = r / B, b = r % B;   // heavy scale-0 rows dispatched first
  const ScaleParams P = (s == 0) ? p0 : (s == 1) ? p1 : p2;
  const int HW = P.HW, N = NA * HW;
  const int t = threadIdx.x;

  for (int i = t; i < 2048; i += BLK) hc[i] = 0u;
  if (t == 0) sh_qn = 0;
  __syncthreads();

  const float* predb = P.pred + (size_t)b * (NA * KCH) * HW;
  const size_t row = (size_t)b * N;
  float nneg = 0.f, posobj = 0.f;

  // ---- sweep 1: obj + masks; counts-only histogram; pos queue ----
  for (int c4 = t * 4; c4 < N; c4 += BLK * 4) {
    const int a = (c4 >= HW) + (c4 >= 2 * HW);
    const int cell = c4 - a * HW;
    const float* pa = predb + (size_t)a * KCH * HW;
    const float4 o4 = *(const float4*)(pa + 4 * HW + cell);
    const uchar4 pm = *(const uchar4*)(P.pos + row + c4);
    const uchar4 nm = *(const uchar4*)(P.neg + row + c4);
    #pragma unroll
    for (int q = 0; q < 4; ++q) {
      const float obj = (&o4.x)[q];
      const float sp = softplus_fast(obj);
      if ((&nm.x)[q]) {
        nneg += 1.f;
        atomicAdd(&hc[__float_as_uint(sp) >> 20], 1u);
      }
      if ((&pm.x)[q]) {
        posobj += sp - obj;
        const int idx = atomicAdd(&sh_qn, 1);
        if (idx < QCAP) queue[idx] = c4 + q;
      }
    }
  }
  __syncthreads();
  const int npos = sh_qn;
  const int qn = min(npos, QCAP);

  // ---- dense pos-anchor processing (CE + smooth-L1), one anchor/thread ----
  float ce = 0.f, loc = 0.f;
  for (int i = t; i < qn; i += BLK) {
    const int j = queue[i];
    const int a = (j >= HW) + (j >= 2 * HW);
    const int cell = j - a * HW;
    const float* pa = predb + (size_t)a * KCH * HW;
    const float c0 = pa[5 * HW + cell];
    const float c1 = pa[6 * HW + cell];
    const float c2 = pa[7 * HW + cell];
    const float m = fmaxf(fmaxf(c0, c1), c2);
    const float e = fexp2((c0 - m) * LOG2E) + fexp2((c1 - m) * LOG2E)
                  + fexp2((c2 - m) * LOG2E);
    const float lse = m + flog2(e) * LN2;
    const int lab = P.labels[row + j];
    ce += lse - ((lab == 0) ? c0 : (lab == 1) ? c1 : c2);
    const float4 bx = *(const float4*)(P.boxes + (size_t)(row + j) * 4);
    loc += sl1f(pa[0 * HW + cell] - bx.x) + sl1f(pa[1 * HW + cell] - bx.y)
         + sl1f(pa[2 * HW + cell] - bx.z) + sl1f(pa[3 * HW + cell] - bx.w);
  }

  const float t_nneg   = blockSum(nneg, fscr);
  const float t_posobj = blockSum(posobj, fscr);
  const float t_ce     = blockSum(ce, fscr);
  const float t_loc    = blockSum(loc, fscr);
  const int nneg_i = (int)t_nneg;
  const int k = min(3 * npos, nneg_i);

  float sel_sum = 0.f;
  if (k > 0) {  // block-uniform
    // ---- stage 1: bits[30:20], counts only ----
    unsigned cb[4]; float sb[4];
    #pragma unroll
    for (int q = 0; q < 4; ++q) { cb[q] = hc[4 * t + q]; sb[q] = 0.f; }
    selectDigit<4>(cb, sb, k, 0.f, iwav, fwav, &sh_dig, &sh_krem, &sh_sa);
    const int bin1 = sh_dig; const int krem1 = sh_krem;

    // ---- sweep 2 (L2-hot re-read): sum above bin1; refine inside bin1 ----
    for (int i = t; i < 2048; i += BLK) { hc[i] = 0u; hs[i] = 0.f; }
    __syncthreads();
    float sgt = 0.f;
    for (int c4 = t * 4; c4 < N; c4 += BLK * 4) {
      const int a = (c4 >= HW) + (c4 >= 2 * HW);
      const int cell = c4 - a * HW;
      const float* pa = predb + (size_t)a * KCH * HW;
      const float4 o4 = *(const float4*)(pa + 4 * HW + cell);
      const uchar4 nm = *(const uchar4*)(P.neg + row + c4);
      #pragma unroll
      for (int q = 0; q < 4; ++q) {
        if ((&nm.x)[q]) {
          const float sp = softplus_fast((&o4.x)[q]);
          const unsigned key = __float_as_uint(sp);
          const int hi = (int)(key >> 20);
          if (hi > bin1) sgt += sp;
          else if (hi == bin1) {
            atomicAdd(&hc[(key >> 9) & 2047], 1u);
            atomicAdd(&hs[(key >> 9) & 2047], sp);
          }
        }
      }
    }
    __syncthreads();
    const float t_sgt = blockSum(sgt, fscr);
    unsigned cb2[4]; float sb2[4];
    #pragma unroll
    for (int q = 0; q < 4; ++q) { cb2[q] = hc[4 * t + q]; sb2[q] = hs[4 * t + q]; }
    selectDigit<4>(cb2, sb2, krem1, t_sgt, iwav, fwav, &sh_dig, &sh_krem, &sh_sa);

    // 22-bit prefix edge approx: error < krem2 * T * 2^-14 — negligible.
    const unsigned Tbits = (((unsigned)bin1 << 11) | (unsigned)sh_dig) << 9;
    sel_sum = sh_sa + (float)sh_krem * __uint_as_float(Tbits);
  }

  if (t == 0) {
    const float denom = (float)max(npos, 1);
    atomicAdd(&out[1], (t_posobj + sel_sum) / denom);
    if (npos > 0) {
      atomicAdd(&out[2], t_ce / denom);
      atomicAdd(&out[3], t_loc / (denom * 4.f));
    }
    __threadfence();
    const unsigned old = atomicAdd(done, 1u);
    if (old == (unsigned)(R - 1)) {   // last block finalizes in place
      const float o = atomicAdd(&out[1], 0.f) * invB;
      const float c = atomicAdd(&out[2], 0.f) * invB;
      const float l = atomicAdd(&out[3], 0.f) * invB;
      out[0] = o + c + l;
      out[1] = o;
      out[2] = c;
      out[3] = l;
    }
  }
}

extern "C" void kernel_launch(void* const* d_in, const int* in_sizes, int n_in,
                              void* d_out, int out_size, void* d_ws, size_t ws_size,
                              hipStream_t stream) {
  (void)n_in; (void)out_size; (void)ws_size;

  const int HW0 = 80 * 80, HW1 = 40 * 40, HW2 = 20 * 20;
  const int B = in_sizes[0] / (NA * KCH * HW0);
  const int R = 3 * B;

  ScaleParams p0{(const float*)d_in[0],  (const float*)d_in[1],
                 (const int*)d_in[2],    (const uint8_t*)d_in[3],
                 (const uint8_t*)d_in[4], HW0};
  ScaleParams p1{(const float*)d_in[5],  (const float*)d_in[6],
                 (const int*)d_in[7],    (const uint8_t*)d_in[8],
                 (const uint8_t*)d_in[9], HW1};
  ScaleParams p2{(const float*)d_in[10], (const float*)d_in[11],
                 (const int*)d_in[12],   (const uint8_t*)d_in[13],
                 (const uint8_t*)d_in[14], HW2};

  float* out = (float*)d_out;
  unsigned* done = (unsigned*)d_ws;

  zero_kernel<<<1, 64, 0, stream>>>(out, done);
  fused_kernel<<<R, BLK, 0, stream>>>(p0, p1, p2, B, R, 1.f / (float)B, out, done);
}